// Round 7
// baseline (291.600 us; speedup 1.0000x reference)
//
#include <hip/hip_runtime.h>
#include <hip/hip_bf16.h>
#include <math.h>

// Problem constants: B=8, S=1000, E=1024, H=16, D=64
constexpr int B_ = 8, S_ = 1000, E_ = 1024, H_ = 16, D_ = 64;
constexpr int M_ = B_ * S_;   // 8000 rows

using bf16x8 = __attribute__((ext_vector_type(8))) __bf16;
using u16x8  = __attribute__((ext_vector_type(8))) unsigned short;
using f32x4  = __attribute__((ext_vector_type(4))) float;

static __device__ __forceinline__ unsigned short f2bf(float f) {
    union { float f; unsigned u; } c; c.f = f;
    return (unsigned short)((c.u + 0x7FFF + ((c.u >> 16) & 1)) >> 16);
}
static __device__ __forceinline__ unsigned short f2bf_fast(float f) {
    union { float f; unsigned u; } c; c.f = f;
    return (unsigned short)((c.u + 0x8000) >> 16);   // round-half-up
}
static __device__ __forceinline__ float bfr2f(unsigned short s) {
    union { unsigned u; float f; } c; c.u = ((unsigned)s) << 16;
    return c.f;
}

// Async global->LDS DMA, 16B per lane. LDS dest is wave-uniform base;
// HW writes base + lane*16 (linear). Global source is per-lane.
static __device__ __forceinline__ void gld16(const unsigned short* g, unsigned short* lds) {
    __builtin_amdgcn_global_load_lds(
        (__attribute__((address_space(1))) void*)(g),
        (__attribute__((address_space(3))) void*)(lds), 16, 0, 0);
}

// ---------------------------------------------------------------------------
// Cast x (fp32 [M,E]) -> bf16.
// ---------------------------------------------------------------------------
__global__ __launch_bounds__(256) void cast_x_kernel(
    const float* __restrict__ x, unsigned short* __restrict__ xbf)
{
    const size_t i = ((size_t)blockIdx.x * 256 + threadIdx.x) * 4;
    float4 v = *(const float4*)(x + i);
    ushort4 o;
    o.x = f2bf(v.x); o.y = f2bf(v.y); o.z = f2bf(v.z); o.w = f2bf(v.w);
    *(ushort4*)(xbf + i) = o;
}

// ---------------------------------------------------------------------------
// Transpose+cast qkv weights: w[h][e][d] fp32 -> WT[(z*16+h)*64 + d][e] bf16.
// ---------------------------------------------------------------------------
__global__ __launch_bounds__(256) void transpose_wqkv_kernel(
    const float* __restrict__ wq, const float* __restrict__ wk,
    const float* __restrict__ wv, unsigned short* __restrict__ WT)
{
    __shared__ unsigned short Ts[64 * 65];
    const int et = blockIdx.x, zh = blockIdx.y;
    const int z = zh >> 4, h = zh & 15;
    const float* src = (z == 0 ? wq : z == 1 ? wk : wv) + (size_t)h * E_ * D_;

    const int d = threadIdx.x & 63;
    const int e0 = threadIdx.x >> 6;   // 0..3
    #pragma unroll
    for (int p = 0; p < 16; ++p) {
        const int e = e0 + p * 4;
        Ts[d * 65 + e] = f2bf(src[(size_t)(et * 64 + e) * D_ + d]);
    }
    __syncthreads();
    const int e = threadIdx.x & 63;
    const int d0 = threadIdx.x >> 6;
    #pragma unroll
    for (int p = 0; p < 16; ++p) {
        const int dd = d0 + p * 4;
        WT[((size_t)zh * 64 + dd) * E_ + et * 64 + e] = Ts[dd * 65 + e];
    }
}

// ---------------------------------------------------------------------------
// Transpose+cast wp: wp[e][f] fp32 -> wpT[f][e] bf16. grid (16 e, 16 f).
// ---------------------------------------------------------------------------
__global__ __launch_bounds__(256) void transpose_wp_kernel(
    const float* __restrict__ wp, unsigned short* __restrict__ wpT)
{
    __shared__ unsigned short Ts[64 * 65];
    const int et = blockIdx.x, ft = blockIdx.y;
    const int f = threadIdx.x & 63;
    const int e0 = threadIdx.x >> 6;
    #pragma unroll
    for (int p = 0; p < 16; ++p) {
        const int e = e0 + p * 4;
        Ts[f * 65 + e] = f2bf(wp[(size_t)(et * 64 + e) * E_ + ft * 64 + f]);
    }
    __syncthreads();
    const int e = threadIdx.x & 63;
    const int f0 = threadIdx.x >> 6;
    #pragma unroll
    for (int p = 0; p < 16; ++p) {
        const int ff = f0 + p * 4;
        wpT[((size_t)(ft * 64 + ff)) * E_ + et * 64 + e] = Ts[ff * 65 + e];
    }
}

// ---------------------------------------------------------------------------
// qkv projection: ONE dense GEMM [M=8000,K=1024] x [K,N=3072].
// 2-barrier single-buffer m97 form (measured best: 90.6us ladder; dbuf and
// XCD-swizzle both regress — see R11-R14 post-mortems. Do not revisit).
// R16 fusions in the EPILOGUE only:
//   - z==0 (q): pre-scaled by 1/sqrt(S)*log2e, so attn skips its Q-scale
//     pass (one fewer bf16 rounding step).
//   - z==2 (v): written directly TRANSPOSED [bh][d][S] -> transpose_v
//     kernel deleted. Store count unchanged (64x 2B scalar/thread); each
//     block fully covers every 64B line it touches (all d, 128 consecutive
//     s), so L2 write-merge behavior is identical to the [s][d] layout.
// ---------------------------------------------------------------------------
__global__ __launch_bounds__(256) void qkv_mfma_kernel(
    const unsigned short* __restrict__ xbf, const unsigned short* __restrict__ WT,
    const float* __restrict__ bq, const float* __restrict__ bk,
    const float* __restrict__ bv,
    unsigned short* __restrict__ qb, unsigned short* __restrict__ kb,
    unsigned short* __restrict__ vt)
{
    __shared__ unsigned short As[128 * 64];   // 16 KB, linear [row][64]
    __shared__ unsigned short Bs[128 * 64];   // 16 KB, linear [nrow][64]

    const int tid  = threadIdx.x;
    const int wave = tid >> 6, lane = tid & 63;
    const int m16  = lane & 15, quad = lane >> 4;
    const int wm   = wave >> 1, wn = wave & 1;
    const int n0   = blockIdx.x * 128;
    const int m0   = blockIdx.y * 128;

    f32x4 acc[4][4];   // [nf][mf]
    #pragma unroll
    for (int nf = 0; nf < 4; ++nf)
        #pragma unroll
        for (int mf = 0; mf < 4; ++mf)
            acc[nf][mf] = (f32x4){0.f, 0.f, 0.f, 0.f};

    const int lrow = lane >> 3;          // 0..7
    const int lcol = (lane & 7) << 3;    // 0,8,..,56

    int a_srow[4];
    #pragma unroll
    for (int j = 0; j < 4; ++j) {
        int r = m0 + (wave * 4 + j) * 8 + lrow;
        a_srow[j] = (r < M_) ? r : (M_ - 1);
    }

    for (int kk = 0; kk < E_; kk += 64) {
        __syncthreads();
        #pragma unroll
        for (int j = 0; j < 4; ++j) {
            const int i = wave * 4 + j;
            gld16(xbf + (size_t)a_srow[j] * E_ + kk + lcol, &As[i * 512]);
            gld16(WT + (size_t)(n0 + i * 8 + lrow) * E_ + kk + lcol, &Bs[i * 512]);
        }
        __syncthreads();

        #pragma unroll
        for (int kh = 0; kh < 2; ++kh) {
            const int ko = kh * 32 + quad * 8;
            bf16x8 af[4];
            #pragma unroll
            for (int mf = 0; mf < 4; ++mf)
                af[mf] = *(const bf16x8*)&As[(wm * 64 + mf * 16 + m16) * 64 + ko];
            #pragma unroll
            for (int nf = 0; nf < 4; ++nf) {
                const bf16x8 bfr = *(const bf16x8*)&Bs[(wn * 64 + nf * 16 + m16) * 64 + ko];
                #pragma unroll
                for (int mf = 0; mf < 4; ++mf)
                    acc[nf][mf] = __builtin_amdgcn_mfma_f32_16x16x32_bf16(
                        af[mf], bfr, acc[nf][mf], 0, 0, 0);
            }
        }
    }

    const int z = n0 >> 10;                 // block-uniform
    const int h = ((n0 >> 6) + wn) & 15;    // wave-uniform

    if (z == 2) {
        // v: write transposed [bh][d][S]
        float biasv[4];
        #pragma unroll
        for (int nf = 0; nf < 4; ++nf)
            biasv[nf] = bv[h * D_ + nf * 16 + m16];

        #pragma unroll
        for (int mf = 0; mf < 4; ++mf)
            #pragma unroll
            for (int r = 0; r < 4; ++r) {
                const int row = m0 + wm * 64 + mf * 16 + quad * 4 + r;
                if (row < M_) {
                    const int b = row / S_, s = row % S_;
                    const size_t vtb = ((size_t)b * H_ + h) * (size_t)(D_ * S_);
                    #pragma unroll
                    for (int nf = 0; nf < 4; ++nf)
                        vt[vtb + (size_t)(nf * 16 + m16) * S_ + s] =
                            f2bf(acc[nf][mf][r] + biasv[nf]);
                }
            }
    } else {
        // q (pre-scaled) or k, layout [b][h][s][d]
        const float qscale = (z == 0)
            ? (0.031622776601683794f * 1.4426950408889634f) : 1.0f;
        unsigned short* const ob = (z == 0) ? qb : kb;
        const float* const bz    = (z == 0) ? bq : bk;

        float biasv[4];
        #pragma unroll
        for (int nf = 0; nf < 4; ++nf)
            biasv[nf] = bz[h * D_ + nf * 16 + m16];

        #pragma unroll
        for (int mf = 0; mf < 4; ++mf)
            #pragma unroll
            for (int r = 0; r < 4; ++r) {
                const int row = m0 + wm * 64 + mf * 16 + quad * 4 + r;
                if (row < M_) {
                    const int b = row / S_, s = row % S_;
                    const size_t obase = (((size_t)b * H_ + h) * S_ + s) * D_ + m16;
                    #pragma unroll
                    for (int nf = 0; nf < 4; ++nf)
                        ob[obase + nf * 16] =
                            f2bf((acc[nf][mf][r] + biasv[nf]) * qscale);
                }
            }
    }
}

// ---------------------------------------------------------------------------
// Flash attention. 8 waves (512 thr), QBLK=128, KVBLK=64 (R15-proven).
// R16: q arrives PRE-SCALED from qkv -> Q staging is a pure copy done with
// gld16 into a LINEAR region of QP (fragments are read once per wave, so
// the 16-way-conflict read pattern there is paid twice per wave — nil).
// QP union: Q staging needs 128*64=8192 shorts; Ps needs 8*16*72=9216 ->
// QP[9216]. Safety: all fragment reads complete before each wave's first
// in-loop barrier (compiler drains lgkmcnt at s_barrier); all Ps writes
// happen after that barrier -> no overlap hazard.
// ---------------------------------------------------------------------------
__global__ __launch_bounds__(512) void attn_flash_kernel(
    const unsigned short* __restrict__ q, const unsigned short* __restrict__ k,
    const unsigned short* __restrict__ vt, unsigned short* __restrict__ ybf)
{
    constexpr int P_ = 72;
    __shared__ unsigned short QP[9216];      // Q staging (8192) / Ps[8][16*P_]
    __shared__ unsigned short Ks[64 * P_];
    __shared__ unsigned short Vt[64 * P_];   // [d][t]

    const int tid  = threadIdx.x;
    const int wave = tid >> 6, lane = tid & 63;
    const int m16  = lane & 15, quad = lane >> 4;
    const int jq = (int)gridDim.x - 1 - (int)blockIdx.x;   // long blocks first
    const int h = blockIdx.y, b = blockIdx.z;
    const size_t bh  = ((size_t)b * H_ + h) * S_;
    const size_t vtb = ((size_t)b * H_ + h) * (size_t)D_ * S_;

    const int c8 = (tid & 7) * 8;
    const int r0 = tid >> 3;   // 0..63

    // stage Q (pre-scaled) via DMA: 16 issues x 1024B cover 128 rows
    #pragma unroll
    for (int j = 0; j < 2; ++j) {
        const int i = wave * 2 + j;              // 0..15, wave-uniform
        int srow = jq * 128 + i * 8 + (lane >> 3);
        if (srow >= S_) srow = S_ - 1;           // clamp: valid data, unused rows
        gld16(q + (bh + srow) * D_ + (lane & 7) * 8, &QP[i * 512]);
    }
    __syncthreads();

    const bf16x8 qa0 = *(const bf16x8*)&QP[(wave * 16 + m16) * 64 + quad * 8];
    const bf16x8 qa1 = *(const bf16x8*)&QP[(wave * 16 + m16) * 64 + 32 + quad * 8];

    f32x4 O[4] = {{0,0,0,0},{0,0,0,0},{0,0,0,0},{0,0,0,0}};
    float l_i[4] = {0.f, 0.f, 0.f, 0.f};

    const int qrow_base = jq * 128 + wave * 16 + quad * 4;
    const int nt = 2 * jq + 2;   // 64-key tiles for this q-block

    // register prefetch of tile 0 (keys 0..63, always valid)
    u16x8 kreg = *(const u16x8*)(k + (bh + r0) * D_ + c8);
    u16x8 vreg = *(const u16x8*)(vt + vtb + (size_t)r0 * S_ + c8);

    for (int tt = 0; tt < nt; ++tt) {
        const int t0 = tt * 64;
        __syncthreads();
        *(u16x8*)&Ks[r0 * P_ + c8] = kreg;
        *(u16x8*)&Vt[r0 * P_ + c8] = vreg;
        __syncthreads();

        if (tt + 1 < nt) {
            const int nt0 = t0 + 64;
            const int srow = nt0 + r0;
            u16x8 kv = {0,0,0,0,0,0,0,0}, vv = {0,0,0,0,0,0,0,0};
            if (srow < S_) kv = *(const u16x8*)(k + (bh + srow) * D_ + c8);
            if (nt0 + c8 < S_)
                vv = *(const u16x8*)(vt + vtb + (size_t)r0 * S_ + nt0 + c8);
            kreg = kv; vreg = vv;
        }

        f32x4 sc[4];
        __builtin_amdgcn_s_setprio(1);
        #pragma unroll
        for (int ts = 0; ts < 4; ++ts) {
            const bf16x8 kb0 = *(const bf16x8*)&Ks[(ts * 16 + m16) * P_ + quad * 8];
            const bf16x8 kb1 = *(const bf16x8*)&Ks[(ts * 16 + m16) * P_ + 32 + quad * 8];
            f32x4 a = {0.f, 0.f, 0.f, 0.f};
            a = __builtin_amdgcn_mfma_f32_16x16x32_bf16(qa0, kb0, a, 0, 0, 0);
            a = __builtin_amdgcn_mfma_f32_16x16x32_bf16(qa1, kb1, a, 0, 0, 0);
            sc[ts] = a;
        }
        __builtin_amdgcn_s_setprio(0);

        unsigned short* const pw = &QP[wave * (16 * P_)];
        if (tt >= nt - 2) {
            #pragma unroll
            for (int ts = 0; ts < 4; ++ts) {
                const int t = t0 + ts * 16 + m16;
                #pragma unroll
                for (int r = 0; r < 4; ++r) {
                    float p = __builtin_amdgcn_exp2f(sc[ts][r]);
                    p = (t <= qrow_base + r) ? p : 0.f;
                    pw[(quad * 4 + r) * P_ + ts * 16 + m16] = f2bf_fast(p);
                    l_i[r] += p;
                }
            }
        } else {
            #pragma unroll
            for (int ts = 0; ts < 4; ++ts)
                #pragma unroll
                for (int r = 0; r < 4; ++r) {
                    const float p = __builtin_amdgcn_exp2f(sc[ts][r]);
                    pw[(quad * 4 + r) * P_ + ts * 16 + m16] = f2bf_fast(p);
                    l_i[r] += p;
                }
        }

        const bf16x8 pa0 = *(const bf16x8*)&pw[m16 * P_ + quad * 8];
        const bf16x8 pa1 = *(const bf16x8*)&pw[m16 * P_ + 32 + quad * 8];
        __builtin_amdgcn_s_setprio(1);
        #pragma unroll
        for (int db = 0; db < 4; ++db) {
            const bf16x8 vb0 = *(const bf16x8*)&Vt[(db * 16 + m16) * P_ + quad * 8];
            const bf16x8 vb1 = *(const bf16x8*)&Vt[(db * 16 + m16) * P_ + 32 + quad * 8];
            O[db] = __builtin_amdgcn_mfma_f32_16x16x32_bf16(pa0, vb0, O[db], 0, 0, 0);
            O[db] = __builtin_amdgcn_mfma_f32_16x16x32_bf16(pa1, vb1, O[db], 0, 0, 0);
        }
        __builtin_amdgcn_s_setprio(0);
    }

    #pragma unroll
    for (int off = 1; off < 16; off <<= 1)
        #pragma unroll
        for (int r = 0; r < 4; ++r)
            l_i[r] += __shfl_xor(l_i[r], off, 64);

    #pragma unroll
    for (int r = 0; r < 4; ++r) {
        const int qrow = qrow_base + r;
        if (qrow < S_) {
            const float invl = 1.0f / l_i[r];
            #pragma unroll
            for (int db = 0; db < 4; ++db)
                ybf[((size_t)b * S_ + qrow) * E_ + h * D_ + db * 16 + m16] =
                    f2bf(O[db][r] * invl);
        }
    }
}

// ---------------------------------------------------------------------------
// proj + exact GELU. m97 gload_lds 2-barrier single-buffer (R14-proven).
// grid (63 m-fast, 8 n): 63 consecutive blocks share one 256 KB B-panel.
// ---------------------------------------------------------------------------
__global__ __launch_bounds__(256) void proj_mfma_kernel(
    const unsigned short* __restrict__ ybf, const unsigned short* __restrict__ wpT,
    const float* __restrict__ bp, float* __restrict__ out)
{
    __shared__ unsigned short As[128 * 64];   // 16 KB, linear
    __shared__ unsigned short Bs[128 * 64];   // 16 KB, linear

    const int tid = threadIdx.x;
    const int wave = tid >> 6, lane = tid & 63;
    const int m16 = lane & 15, quad = lane >> 4;
    const int wm = wave >> 1, wn = wave & 1;
    const int m0 = blockIdx.x * 128;
    const int n0 = blockIdx.y * 128;

    f32x4 acc[4][4];
    #pragma unroll
    for (int nf = 0; nf < 4; ++nf)
        #pragma unroll
        for (int mf = 0; mf < 4; ++mf)
            acc[nf][mf] = (f32x4){0.f, 0.f, 0.f, 0.f};

    const int lrow = lane >> 3;          // 0..7
    const int lcol = (lane & 7) << 3;    // 0,8,..,56

    int a_srow[4];
    #pragma unroll
    for (int j = 0; j < 4; ++j) {
        int r = m0 + (wave * 4 + j) * 8 + lrow;
        a_srow[j] = (r < M_) ? r : (M_ - 1);
    }

    for (int kk = 0; kk < E_; kk += 64) {
        __syncthreads();
        #pragma unroll
        for (int j = 0; j < 4; ++j) {
            const int i = wave * 4 + j;
            gld16(ybf + (size_t)a_srow[j] * E_ + kk + lcol, &As[i * 512]);
            gld16(wpT + (size_t)(n0 + i * 8 + lrow) * E_ + kk + lcol, &Bs[i * 512]);
        }
        __syncthreads();

        #pragma unroll
        for (int kh = 0; kh < 2; ++kh) {
            const int ko = kh * 32 + quad * 8;
            bf16x8 af[4];
            #pragma unroll
            for (int mf = 0; mf < 4; ++mf)
                af[mf] = *(const bf16x8*)&As[(wm * 64 + mf * 16 + m16) * 64 + ko];
            #pragma unroll
            for (int nf = 0; nf < 4; ++nf) {
                const bf16x8 bfr = *(const bf16x8*)&Bs[(wn * 64 + nf * 16 + m16) * 64 + ko];
                #pragma unroll
                for (int mf = 0; mf < 4; ++mf)
                    acc[nf][mf] = __builtin_amdgcn_mfma_f32_16x16x32_bf16(
                        af[mf], bfr, acc[nf][mf], 0, 0, 0);
            }
        }
    }

    float biasv[4];
    #pragma unroll
    for (int nf = 0; nf < 4; ++nf)
        biasv[nf] = bp[n0 + wn * 64 + nf * 16 + m16];

    #pragma unroll
    for (int mf = 0; mf < 4; ++mf)
        #pragma unroll
        for (int r = 0; r < 4; ++r) {
            const int row = m0 + wm * 64 + mf * 16 + quad * 4 + r;
            if (row < M_) {
                #pragma unroll
                for (int nf = 0; nf < 4; ++nf) {
                    const int col = n0 + wn * 64 + nf * 16 + m16;
                    const float t = acc[nf][mf][r] + biasv[nf];
                    const float g = 0.5f * t * (1.0f + erff(t * 0.70710678118654752f));
                    out[(size_t)row * E_ + col] = g;
                }
            }
        }
}

// ---------------------------------------------------------------------------
extern "C" void kernel_launch(void* const* d_in, const int* in_sizes, int n_in,
                              void* d_out, int out_size, void* d_ws, size_t ws_size,
                              hipStream_t stream)
{
    const float* x  = (const float*)d_in[0];
    const float* wq = (const float*)d_in[1];
    const float* bq = (const float*)d_in[2];
    const float* wk = (const float*)d_in[3];
    const float* bk = (const float*)d_in[4];
    const float* wv = (const float*)d_in[5];
    const float* bv = (const float*)d_in[6];
    const float* wp = (const float*)d_in[7];
    const float* bp = (const float*)d_in[8];
    float* out = (float*)d_out;

    const size_t nME = (size_t)M_ * E_;          // 8,192,000
    unsigned short* xbf = (unsigned short*)d_ws;
    unsigned short* WT  = xbf + nME;             // 3,145,728
    unsigned short* wpT = WT + 3145728;          // 1,048,576
    unsigned short* qb  = wpT + 1048576;
    unsigned short* kb  = qb + nME;
    unsigned short* vtr = kb + nME;              // v transposed [bh][d][S] (direct from qkv)
    unsigned short* ybf = vtr + nME;

    cast_x_kernel<<<dim3((unsigned)(nME / 1024)), 256, 0, stream>>>(x, xbf);
    transpose_wqkv_kernel<<<dim3(16, 48), 256, 0, stream>>>(wq, wk, wv, WT);
    transpose_wp_kernel<<<dim3(16, 16), 256, 0, stream>>>(wp, wpT);

    // Single-GEMM qkv: grid (N-tiles=24 fastest, M-tiles=63).
    // Writes q pre-scaled, k, and v directly transposed (no transpose_v).
    qkv_mfma_kernel<<<dim3(3072 / 128, (M_ + 127) / 128), 256, 0, stream>>>(
        xbf, WT, bq, bk, bv, qb, kb, vtr);
    attn_flash_kernel<<<dim3((S_ + 127) / 128, H_, B_), 512, 0, stream>>>(
        qb, kb, vtr, ybf);
    proj_mfma_kernel<<<dim3((M_ + 127) / 128, E_ / 128), 256, 0, stream>>>(
        ybf, wpT, bp, out);
}

// Round 8
// 279.143 us; speedup vs baseline: 1.0446x; 1.0446x over previous
//
#include <hip/hip_runtime.h>
#include <hip/hip_bf16.h>
#include <math.h>

// Problem constants: B=8, S=1000, E=1024, H=16, D=64
constexpr int B_ = 8, S_ = 1000, E_ = 1024, H_ = 16, D_ = 64;
constexpr int M_ = B_ * S_;   // 8000 rows

using bf16x8 = __attribute__((ext_vector_type(8))) __bf16;
using u16x8  = __attribute__((ext_vector_type(8))) unsigned short;
using f32x4  = __attribute__((ext_vector_type(4))) float;

static __device__ __forceinline__ unsigned short f2bf(float f) {
    union { float f; unsigned u; } c; c.f = f;
    return (unsigned short)((c.u + 0x7FFF + ((c.u >> 16) & 1)) >> 16);
}
static __device__ __forceinline__ unsigned short f2bf_fast(float f) {
    union { float f; unsigned u; } c; c.f = f;
    return (unsigned short)((c.u + 0x8000) >> 16);   // round-half-up
}
static __device__ __forceinline__ float bfr2f(unsigned short s) {
    union { unsigned u; float f; } c; c.u = ((unsigned)s) << 16;
    return c.f;
}

// Async global->LDS DMA, 16B per lane. LDS dest is wave-uniform base;
// HW writes base + lane*16 (linear). Global source is per-lane.
static __device__ __forceinline__ void gld16(const unsigned short* g, unsigned short* lds) {
    __builtin_amdgcn_global_load_lds(
        (__attribute__((address_space(1))) void*)(g),
        (__attribute__((address_space(3))) void*)(lds), 16, 0, 0);
}

// ---------------------------------------------------------------------------
// Cast x (fp32 [M,E]) -> bf16.
// ---------------------------------------------------------------------------
__global__ __launch_bounds__(256) void cast_x_kernel(
    const float* __restrict__ x, unsigned short* __restrict__ xbf)
{
    const size_t i = ((size_t)blockIdx.x * 256 + threadIdx.x) * 4;
    float4 v = *(const float4*)(x + i);
    ushort4 o;
    o.x = f2bf(v.x); o.y = f2bf(v.y); o.z = f2bf(v.z); o.w = f2bf(v.w);
    *(ushort4*)(xbf + i) = o;
}

// ---------------------------------------------------------------------------
// Transpose+cast qkv weights: w[h][e][d] fp32 -> WT[(z*16+h)*64 + d][e] bf16.
// ---------------------------------------------------------------------------
__global__ __launch_bounds__(256) void transpose_wqkv_kernel(
    const float* __restrict__ wq, const float* __restrict__ wk,
    const float* __restrict__ wv, unsigned short* __restrict__ WT)
{
    __shared__ unsigned short Ts[64 * 65];
    const int et = blockIdx.x, zh = blockIdx.y;
    const int z = zh >> 4, h = zh & 15;
    const float* src = (z == 0 ? wq : z == 1 ? wk : wv) + (size_t)h * E_ * D_;

    const int d = threadIdx.x & 63;
    const int e0 = threadIdx.x >> 6;   // 0..3
    #pragma unroll
    for (int p = 0; p < 16; ++p) {
        const int e = e0 + p * 4;
        Ts[d * 65 + e] = f2bf(src[(size_t)(et * 64 + e) * D_ + d]);
    }
    __syncthreads();
    const int e = threadIdx.x & 63;
    const int d0 = threadIdx.x >> 6;
    #pragma unroll
    for (int p = 0; p < 16; ++p) {
        const int dd = d0 + p * 4;
        WT[((size_t)zh * 64 + dd) * E_ + et * 64 + e] = Ts[dd * 65 + e];
    }
}

// ---------------------------------------------------------------------------
// Transpose+cast wp: wp[e][f] fp32 -> wpT[f][e] bf16. grid (16 e, 16 f).
// ---------------------------------------------------------------------------
__global__ __launch_bounds__(256) void transpose_wp_kernel(
    const float* __restrict__ wp, unsigned short* __restrict__ wpT)
{
    __shared__ unsigned short Ts[64 * 65];
    const int et = blockIdx.x, ft = blockIdx.y;
    const int f = threadIdx.x & 63;
    const int e0 = threadIdx.x >> 6;
    #pragma unroll
    for (int p = 0; p < 16; ++p) {
        const int e = e0 + p * 4;
        Ts[f * 65 + e] = f2bf(wp[(size_t)(et * 64 + e) * E_ + ft * 64 + f]);
    }
    __syncthreads();
    const int e = threadIdx.x & 63;
    const int f0 = threadIdx.x >> 6;
    #pragma unroll
    for (int p = 0; p < 16; ++p) {
        const int ff = f0 + p * 4;
        wpT[((size_t)(ft * 64 + ff)) * E_ + et * 64 + e] = Ts[ff * 65 + e];
    }
}

// ---------------------------------------------------------------------------
// qkv projection: ONE dense GEMM [M=8000,K=1024] x [K,N=3072].
// 2-barrier single-buffer m97 form (measured best; dbuf/XCD-swizzle regress,
// see R11-R14). Epilogue fusions:
//   - z==0 (q): pre-scaled by 1/sqrt(S)*log2e (attn skips its scale pass).
//   - z==2 (v): written TRANSPOSED [bh][d][S] via LDS-staged coalesce.
// R16 post-mortem: direct transposed scatter = 16 lanes/quad writing same s
// at 16 different d (stride 2000B) -> 64 lines per wave-store, qkv 90->106us
// with WRITE_SIZE unchanged (issue-bound, not traffic). Fix: stage the
// 128x128 tile in LDS (reuse As+Bs, dead after K-loop) with 16B-block XOR
// swizzle, then stream rows coalesced (256B contiguous per 16-lane group).
// ---------------------------------------------------------------------------
__global__ __launch_bounds__(256) void qkv_mfma_kernel(
    const unsigned short* __restrict__ xbf, const unsigned short* __restrict__ WT,
    const float* __restrict__ bq, const float* __restrict__ bk,
    const float* __restrict__ bv,
    unsigned short* __restrict__ qb, unsigned short* __restrict__ kb,
    unsigned short* __restrict__ vt)
{
    __shared__ unsigned short Sh[2 * 128 * 64];   // 32 KB: As | Bs, reused as Ts
    unsigned short* const As = Sh;
    unsigned short* const Bs = Sh + 128 * 64;

    const int tid  = threadIdx.x;
    const int wave = tid >> 6, lane = tid & 63;
    const int m16  = lane & 15, quad = lane >> 4;
    const int wm   = wave >> 1, wn = wave & 1;
    const int n0   = blockIdx.x * 128;
    const int m0   = blockIdx.y * 128;

    f32x4 acc[4][4];   // [nf][mf]
    #pragma unroll
    for (int nf = 0; nf < 4; ++nf)
        #pragma unroll
        for (int mf = 0; mf < 4; ++mf)
            acc[nf][mf] = (f32x4){0.f, 0.f, 0.f, 0.f};

    const int lrow = lane >> 3;          // 0..7
    const int lcol = (lane & 7) << 3;    // 0,8,..,56

    int a_srow[4];
    #pragma unroll
    for (int j = 0; j < 4; ++j) {
        int r = m0 + (wave * 4 + j) * 8 + lrow;
        a_srow[j] = (r < M_) ? r : (M_ - 1);
    }

    for (int kk = 0; kk < E_; kk += 64) {
        __syncthreads();
        #pragma unroll
        for (int j = 0; j < 4; ++j) {
            const int i = wave * 4 + j;
            gld16(xbf + (size_t)a_srow[j] * E_ + kk + lcol, &As[i * 512]);
            gld16(WT + (size_t)(n0 + i * 8 + lrow) * E_ + kk + lcol, &Bs[i * 512]);
        }
        __syncthreads();

        #pragma unroll
        for (int kh = 0; kh < 2; ++kh) {
            const int ko = kh * 32 + quad * 8;
            bf16x8 af[4];
            #pragma unroll
            for (int mf = 0; mf < 4; ++mf)
                af[mf] = *(const bf16x8*)&As[(wm * 64 + mf * 16 + m16) * 64 + ko];
            #pragma unroll
            for (int nf = 0; nf < 4; ++nf) {
                const bf16x8 bfr = *(const bf16x8*)&Bs[(wn * 64 + nf * 16 + m16) * 64 + ko];
                #pragma unroll
                for (int mf = 0; mf < 4; ++mf)
                    acc[nf][mf] = __builtin_amdgcn_mfma_f32_16x16x32_bf16(
                        af[mf], bfr, acc[nf][mf], 0, 0, 0);
            }
        }
    }

    const int z = n0 >> 10;                 // block-uniform
    const int h = ((n0 >> 6) + wn) & 15;    // wave-uniform

    if (z == 2) {
        // v -> transposed [bh][d][S] via LDS-staged coalesced write.
        float biasv[4];
        #pragma unroll
        for (int nf = 0; nf < 4; ++nf)
            biasv[nf] = bv[h * D_ + nf * 16 + m16];

        __syncthreads();   // all waves' final As/Bs reads done before reuse
        // scatter acc -> Ts[128n][128m], 16B-block XOR swizzle on short idx
        #pragma unroll
        for (int mf = 0; mf < 4; ++mf)
            #pragma unroll
            for (int r = 0; r < 4; ++r) {
                const int ml = wm * 64 + mf * 16 + quad * 4 + r;   // 0..127
                #pragma unroll
                for (int nf = 0; nf < 4; ++nf) {
                    const int nl = wn * 64 + nf * 16 + m16;        // 0..127
                    const int idx = (nl * 128 + ml) ^ ((nl & 7) << 3);
                    Sh[idx] = f2bf(acc[nf][mf][r] + biasv[nf]);
                }
            }
        __syncthreads();
        // coalesced stream-out: 8 passes x 256 thr x 8 shorts = 128x128
        #pragma unroll
        for (int p = 0; p < 8; ++p) {
            const int idxl  = p * 256 + tid;       // 0..2047
            const int row   = idxl >> 4;           // n-local 0..127
            const int chunk = idxl & 15;           // 16B chunk within row
            const int mg    = m0 + chunk * 8;      // global m base (8-aligned)
            if (mg < M_) {                          // batch bdry 1000%8==0: no straddle
                const int bb = mg / S_, ss = mg % S_;
                const int hh = ((n0 >> 6) + (row >> 6)) & 15;
                const int dd = row & 63;
                const int sidx = (row * 128 + chunk * 8) ^ ((row & 7) << 3);
                *(u16x8*)(vt + ((size_t)bb * H_ + hh) * (size_t)(D_ * S_)
                              + (size_t)dd * S_ + ss) = *(const u16x8*)&Sh[sidx];
            }
        }
    } else {
        // q (pre-scaled) or k, layout [b][h][s][d]
        const float qscale = (z == 0)
            ? (0.031622776601683794f * 1.4426950408889634f) : 1.0f;
        unsigned short* const ob = (z == 0) ? qb : kb;
        const float* const bz    = (z == 0) ? bq : bk;

        float biasv[4];
        #pragma unroll
        for (int nf = 0; nf < 4; ++nf)
            biasv[nf] = bz[h * D_ + nf * 16 + m16];

        #pragma unroll
        for (int mf = 0; mf < 4; ++mf)
            #pragma unroll
            for (int r = 0; r < 4; ++r) {
                const int row = m0 + wm * 64 + mf * 16 + quad * 4 + r;
                if (row < M_) {
                    const int b = row / S_, s = row % S_;
                    const size_t obase = (((size_t)b * H_ + h) * S_ + s) * D_ + m16;
                    #pragma unroll
                    for (int nf = 0; nf < 4; ++nf)
                        ob[obase + nf * 16] =
                            f2bf((acc[nf][mf][r] + biasv[nf]) * qscale);
                }
            }
    }
}

// ---------------------------------------------------------------------------
// Flash attention. 8 waves (512 thr), QBLK=128, KVBLK=64 (R15-proven).
// q arrives PRE-SCALED -> Q staging is a pure gld16 copy into linear QP.
// QP union: Q staging 8192 shorts / Ps 9216 -> QP[9216]; fragment reads
// complete before the first in-loop barrier, Ps writes after it.
// ---------------------------------------------------------------------------
__global__ __launch_bounds__(512) void attn_flash_kernel(
    const unsigned short* __restrict__ q, const unsigned short* __restrict__ k,
    const unsigned short* __restrict__ vt, unsigned short* __restrict__ ybf)
{
    constexpr int P_ = 72;
    __shared__ unsigned short QP[9216];      // Q staging (8192) / Ps[8][16*P_]
    __shared__ unsigned short Ks[64 * P_];
    __shared__ unsigned short Vt[64 * P_];   // [d][t]

    const int tid  = threadIdx.x;
    const int wave = tid >> 6, lane = tid & 63;
    const int m16  = lane & 15, quad = lane >> 4;
    const int jq = (int)gridDim.x - 1 - (int)blockIdx.x;   // long blocks first
    const int h = blockIdx.y, b = blockIdx.z;
    const size_t bh  = ((size_t)b * H_ + h) * S_;
    const size_t vtb = ((size_t)b * H_ + h) * (size_t)D_ * S_;

    const int c8 = (tid & 7) * 8;
    const int r0 = tid >> 3;   // 0..63

    // stage Q (pre-scaled) via DMA: 16 issues x 1024B cover 128 rows
    #pragma unroll
    for (int j = 0; j < 2; ++j) {
        const int i = wave * 2 + j;              // 0..15, wave-uniform
        int srow = jq * 128 + i * 8 + (lane >> 3);
        if (srow >= S_) srow = S_ - 1;           // clamp: valid data, unused rows
        gld16(q + (bh + srow) * D_ + (lane & 7) * 8, &QP[i * 512]);
    }
    __syncthreads();

    const bf16x8 qa0 = *(const bf16x8*)&QP[(wave * 16 + m16) * 64 + quad * 8];
    const bf16x8 qa1 = *(const bf16x8*)&QP[(wave * 16 + m16) * 64 + 32 + quad * 8];

    f32x4 O[4] = {{0,0,0,0},{0,0,0,0},{0,0,0,0},{0,0,0,0}};
    float l_i[4] = {0.f, 0.f, 0.f, 0.f};

    const int qrow_base = jq * 128 + wave * 16 + quad * 4;
    const int nt = 2 * jq + 2;   // 64-key tiles for this q-block

    // register prefetch of tile 0 (keys 0..63, always valid)
    u16x8 kreg = *(const u16x8*)(k + (bh + r0) * D_ + c8);
    u16x8 vreg = *(const u16x8*)(vt + vtb + (size_t)r0 * S_ + c8);

    for (int tt = 0; tt < nt; ++tt) {
        const int t0 = tt * 64;
        __syncthreads();
        *(u16x8*)&Ks[r0 * P_ + c8] = kreg;
        *(u16x8*)&Vt[r0 * P_ + c8] = vreg;
        __syncthreads();

        if (tt + 1 < nt) {
            const int nt0 = t0 + 64;
            const int srow = nt0 + r0;
            u16x8 kv = {0,0,0,0,0,0,0,0}, vv = {0,0,0,0,0,0,0,0};
            if (srow < S_) kv = *(const u16x8*)(k + (bh + srow) * D_ + c8);
            if (nt0 + c8 < S_)
                vv = *(const u16x8*)(vt + vtb + (size_t)r0 * S_ + nt0 + c8);
            kreg = kv; vreg = vv;
        }

        f32x4 sc[4];
        __builtin_amdgcn_s_setprio(1);
        #pragma unroll
        for (int ts = 0; ts < 4; ++ts) {
            const bf16x8 kb0 = *(const bf16x8*)&Ks[(ts * 16 + m16) * P_ + quad * 8];
            const bf16x8 kb1 = *(const bf16x8*)&Ks[(ts * 16 + m16) * P_ + 32 + quad * 8];
            f32x4 a = {0.f, 0.f, 0.f, 0.f};
            a = __builtin_amdgcn_mfma_f32_16x16x32_bf16(qa0, kb0, a, 0, 0, 0);
            a = __builtin_amdgcn_mfma_f32_16x16x32_bf16(qa1, kb1, a, 0, 0, 0);
            sc[ts] = a;
        }
        __builtin_amdgcn_s_setprio(0);

        unsigned short* const pw = &QP[wave * (16 * P_)];
        if (tt >= nt - 2) {
            #pragma unroll
            for (int ts = 0; ts < 4; ++ts) {
                const int t = t0 + ts * 16 + m16;
                #pragma unroll
                for (int r = 0; r < 4; ++r) {
                    float p = __builtin_amdgcn_exp2f(sc[ts][r]);
                    p = (t <= qrow_base + r) ? p : 0.f;
                    pw[(quad * 4 + r) * P_ + ts * 16 + m16] = f2bf_fast(p);
                    l_i[r] += p;
                }
            }
        } else {
            #pragma unroll
            for (int ts = 0; ts < 4; ++ts)
                #pragma unroll
                for (int r = 0; r < 4; ++r) {
                    const float p = __builtin_amdgcn_exp2f(sc[ts][r]);
                    pw[(quad * 4 + r) * P_ + ts * 16 + m16] = f2bf_fast(p);
                    l_i[r] += p;
                }
        }

        const bf16x8 pa0 = *(const bf16x8*)&pw[m16 * P_ + quad * 8];
        const bf16x8 pa1 = *(const bf16x8*)&pw[m16 * P_ + 32 + quad * 8];
        __builtin_amdgcn_s_setprio(1);
        #pragma unroll
        for (int db = 0; db < 4; ++db) {
            const bf16x8 vb0 = *(const bf16x8*)&Vt[(db * 16 + m16) * P_ + quad * 8];
            const bf16x8 vb1 = *(const bf16x8*)&Vt[(db * 16 + m16) * P_ + 32 + quad * 8];
            O[db] = __builtin_amdgcn_mfma_f32_16x16x32_bf16(pa0, vb0, O[db], 0, 0, 0);
            O[db] = __builtin_amdgcn_mfma_f32_16x16x32_bf16(pa1, vb1, O[db], 0, 0, 0);
        }
        __builtin_amdgcn_s_setprio(0);
    }

    #pragma unroll
    for (int off = 1; off < 16; off <<= 1)
        #pragma unroll
        for (int r = 0; r < 4; ++r)
            l_i[r] += __shfl_xor(l_i[r], off, 64);

    #pragma unroll
    for (int r = 0; r < 4; ++r) {
        const int qrow = qrow_base + r;
        if (qrow < S_) {
            const float invl = 1.0f / l_i[r];
            #pragma unroll
            for (int db = 0; db < 4; ++db)
                ybf[((size_t)b * S_ + qrow) * E_ + h * D_ + db * 16 + m16] =
                    f2bf(O[db][r] * invl);
        }
    }
}

// ---------------------------------------------------------------------------
// proj + exact GELU. m97 gload_lds 2-barrier single-buffer (R14-proven).
// grid (63 m-fast, 8 n): 63 consecutive blocks share one 256 KB B-panel.
// ---------------------------------------------------------------------------
__global__ __launch_bounds__(256) void proj_mfma_kernel(
    const unsigned short* __restrict__ ybf, const unsigned short* __restrict__ wpT,
    const float* __restrict__ bp, float* __restrict__ out)
{
    __shared__ unsigned short As[128 * 64];   // 16 KB, linear
    __shared__ unsigned short Bs[128 * 64];   // 16 KB, linear

    const int tid = threadIdx.x;
    const int wave = tid >> 6, lane = tid & 63;
    const int m16 = lane & 15, quad = lane >> 4;
    const int wm = wave >> 1, wn = wave & 1;
    const int m0 = blockIdx.x * 128;
    const int n0 = blockIdx.y * 128;

    f32x4 acc[4][4];
    #pragma unroll
    for (int nf = 0; nf < 4; ++nf)
        #pragma unroll
        for (int mf = 0; mf < 4; ++mf)
            acc[nf][mf] = (f32x4){0.f, 0.f, 0.f, 0.f};

    const int lrow = lane >> 3;          // 0..7
    const int lcol = (lane & 7) << 3;    // 0,8,..,56

    int a_srow[4];
    #pragma unroll
    for (int j = 0; j < 4; ++j) {
        int r = m0 + (wave * 4 + j) * 8 + lrow;
        a_srow[j] = (r < M_) ? r : (M_ - 1);
    }

    for (int kk = 0; kk < E_; kk += 64) {
        __syncthreads();
        #pragma unroll
        for (int j = 0; j < 4; ++j) {
            const int i = wave * 4 + j;
            gld16(ybf + (size_t)a_srow[j] * E_ + kk + lcol, &As[i * 512]);
            gld16(wpT + (size_t)(n0 + i * 8 + lrow) * E_ + kk + lcol, &Bs[i * 512]);
        }
        __syncthreads();

        #pragma unroll
        for (int kh = 0; kh < 2; ++kh) {
            const int ko = kh * 32 + quad * 8;
            bf16x8 af[4];
            #pragma unroll
            for (int mf = 0; mf < 4; ++mf)
                af[mf] = *(const bf16x8*)&As[(wm * 64 + mf * 16 + m16) * 64 + ko];
            #pragma unroll
            for (int nf = 0; nf < 4; ++nf) {
                const bf16x8 bfr = *(const bf16x8*)&Bs[(wn * 64 + nf * 16 + m16) * 64 + ko];
                #pragma unroll
                for (int mf = 0; mf < 4; ++mf)
                    acc[nf][mf] = __builtin_amdgcn_mfma_f32_16x16x32_bf16(
                        af[mf], bfr, acc[nf][mf], 0, 0, 0);
            }
        }
    }

    float biasv[4];
    #pragma unroll
    for (int nf = 0; nf < 4; ++nf)
        biasv[nf] = bp[n0 + wn * 64 + nf * 16 + m16];

    #pragma unroll
    for (int mf = 0; mf < 4; ++mf)
        #pragma unroll
        for (int r = 0; r < 4; ++r) {
            const int row = m0 + wm * 64 + mf * 16 + quad * 4 + r;
            if (row < M_) {
                #pragma unroll
                for (int nf = 0; nf < 4; ++nf) {
                    const int col = n0 + wn * 64 + nf * 16 + m16;
                    const float t = acc[nf][mf][r] + biasv[nf];
                    const float g = 0.5f * t * (1.0f + erff(t * 0.70710678118654752f));
                    out[(size_t)row * E_ + col] = g;
                }
            }
        }
}

// ---------------------------------------------------------------------------
extern "C" void kernel_launch(void* const* d_in, const int* in_sizes, int n_in,
                              void* d_out, int out_size, void* d_ws, size_t ws_size,
                              hipStream_t stream)
{
    const float* x  = (const float*)d_in[0];
    const float* wq = (const float*)d_in[1];
    const float* bq = (const float*)d_in[2];
    const float* wk = (const float*)d_in[3];
    const float* bk = (const float*)d_in[4];
    const float* wv = (const float*)d_in[5];
    const float* bv = (const float*)d_in[6];
    const float* wp = (const float*)d_in[7];
    const float* bp = (const float*)d_in[8];
    float* out = (float*)d_out;

    const size_t nME = (size_t)M_ * E_;          // 8,192,000
    unsigned short* xbf = (unsigned short*)d_ws;
    unsigned short* WT  = xbf + nME;             // 3,145,728
    unsigned short* wpT = WT + 3145728;          // 1,048,576
    unsigned short* qb  = wpT + 1048576;
    unsigned short* kb  = qb + nME;
    unsigned short* vtr = kb + nME;              // v transposed [bh][d][S] (direct from qkv)
    unsigned short* ybf = vtr + nME;

    cast_x_kernel<<<dim3((unsigned)(nME / 1024)), 256, 0, stream>>>(x, xbf);
    transpose_wqkv_kernel<<<dim3(16, 48), 256, 0, stream>>>(wq, wk, wv, WT);
    transpose_wp_kernel<<<dim3(16, 16), 256, 0, stream>>>(wp, wpT);

    // Single-GEMM qkv: grid (N-tiles=24 fastest, M-tiles=63).
    // Writes q pre-scaled, k, and v directly transposed (no transpose_v).
    qkv_mfma_kernel<<<dim3(3072 / 128, (M_ + 127) / 128), 256, 0, stream>>>(
        xbf, WT, bq, bk, bv, qb, kb, vtr);
    attn_flash_kernel<<<dim3((S_ + 127) / 128, H_, B_), 512, 0, stream>>>(
        qb, kb, vtr, ybf);
    proj_mfma_kernel<<<dim3((M_ + 127) / 128, E_ / 128), 256, 0, stream>>>(
        ybf, wpT, bp, out);
}

// Round 9
// 275.942 us; speedup vs baseline: 1.0567x; 1.0116x over previous
//
#include <hip/hip_runtime.h>
#include <hip/hip_bf16.h>
#include <math.h>

// Problem constants: B=8, S=1000, E=1024, H=16, D=64
constexpr int B_ = 8, S_ = 1000, E_ = 1024, H_ = 16, D_ = 64;
constexpr int M_ = B_ * S_;   // 8000 rows

using bf16x8 = __attribute__((ext_vector_type(8))) __bf16;
using u16x8  = __attribute__((ext_vector_type(8))) unsigned short;
using f32x4  = __attribute__((ext_vector_type(4))) float;

static __device__ __forceinline__ unsigned short f2bf(float f) {
    union { float f; unsigned u; } c; c.f = f;
    return (unsigned short)((c.u + 0x7FFF + ((c.u >> 16) & 1)) >> 16);
}
static __device__ __forceinline__ unsigned short f2bf_fast(float f) {
    union { float f; unsigned u; } c; c.f = f;
    return (unsigned short)((c.u + 0x8000) >> 16);   // round-half-up
}
static __device__ __forceinline__ float bfr2f(unsigned short s) {
    union { unsigned u; float f; } c; c.u = ((unsigned)s) << 16;
    return c.f;
}

// Async global->LDS DMA, 16B per lane. LDS dest is wave-uniform base;
// HW writes base + lane*16 (linear). Global source is per-lane.
static __device__ __forceinline__ void gld16(const unsigned short* g, unsigned short* lds) {
    __builtin_amdgcn_global_load_lds(
        (__attribute__((address_space(1))) void*)(g),
        (__attribute__((address_space(3))) void*)(lds), 16, 0, 0);
}

// ---------------------------------------------------------------------------
// Cast x (fp32 [M,E]) -> bf16.
// ---------------------------------------------------------------------------
__global__ __launch_bounds__(256) void cast_x_kernel(
    const float* __restrict__ x, unsigned short* __restrict__ xbf)
{
    const size_t i = ((size_t)blockIdx.x * 256 + threadIdx.x) * 4;
    float4 v = *(const float4*)(x + i);
    ushort4 o;
    o.x = f2bf(v.x); o.y = f2bf(v.y); o.z = f2bf(v.z); o.w = f2bf(v.w);
    *(ushort4*)(xbf + i) = o;
}

// ---------------------------------------------------------------------------
// R17: merged weight transposes (one launch instead of two).
//   y in [0,48):  w{q,k,v}[h][e][d] fp32 -> WT[(z*16+h)*64+d][e] bf16
//   y in [48,64): wp[e][f] fp32 -> wpT[f][e] bf16, ft = y-48
// ---------------------------------------------------------------------------
__global__ __launch_bounds__(256) void transpose_w_kernel(
    const float* __restrict__ wq, const float* __restrict__ wk,
    const float* __restrict__ wv, const float* __restrict__ wp,
    unsigned short* __restrict__ WT, unsigned short* __restrict__ wpT)
{
    __shared__ unsigned short Ts[64 * 65];
    const int et = blockIdx.x, y = blockIdx.y;

    if (y < 48) {
        const int z = y >> 4, h = y & 15;
        const float* src = (z == 0 ? wq : z == 1 ? wk : wv) + (size_t)h * E_ * D_;
        const int d = threadIdx.x & 63;
        const int e0 = threadIdx.x >> 6;   // 0..3
        #pragma unroll
        for (int p = 0; p < 16; ++p) {
            const int e = e0 + p * 4;
            Ts[d * 65 + e] = f2bf(src[(size_t)(et * 64 + e) * D_ + d]);
        }
        __syncthreads();
        const int e = threadIdx.x & 63;
        const int d0 = threadIdx.x >> 6;
        #pragma unroll
        for (int p = 0; p < 16; ++p) {
            const int dd = d0 + p * 4;
            WT[((size_t)y * 64 + dd) * E_ + et * 64 + e] = Ts[dd * 65 + e];
        }
    } else {
        const int ft = y - 48;
        const int f = threadIdx.x & 63;
        const int e0 = threadIdx.x >> 6;
        #pragma unroll
        for (int p = 0; p < 16; ++p) {
            const int e = e0 + p * 4;
            Ts[f * 65 + e] = f2bf(wp[(size_t)(et * 64 + e) * E_ + ft * 64 + f]);
        }
        __syncthreads();
        const int e = threadIdx.x & 63;
        const int f0 = threadIdx.x >> 6;
        #pragma unroll
        for (int p = 0; p < 16; ++p) {
            const int ff = f0 + p * 4;
            wpT[((size_t)(ft * 64 + ff)) * E_ + et * 64 + e] = Ts[ff * 65 + e];
        }
    }
}

// ---------------------------------------------------------------------------
// qkv projection: ONE dense GEMM [M=8000,K=1024] x [K,N=3072].
// 2-barrier single-buffer m97 form (measured best; dbuf/XCD-swizzle regress,
// see R11-R14). Epilogue fusions (R16/R17-proven, qkv back at 90.2us):
//   - z==0 (q): pre-scaled by 1/sqrt(S)*log2e.
//   - z==2 (v): TRANSPOSED [bh][d][S] via LDS-staged coalesce (direct
//     scatter was issue-bound: 64 lines/wave-store, +16us — R16 lesson).
// ---------------------------------------------------------------------------
__global__ __launch_bounds__(256) void qkv_mfma_kernel(
    const unsigned short* __restrict__ xbf, const unsigned short* __restrict__ WT,
    const float* __restrict__ bq, const float* __restrict__ bk,
    const float* __restrict__ bv,
    unsigned short* __restrict__ qb, unsigned short* __restrict__ kb,
    unsigned short* __restrict__ vt)
{
    __shared__ unsigned short Sh[2 * 128 * 64];   // 32 KB: As | Bs, reused as Ts
    unsigned short* const As = Sh;
    unsigned short* const Bs = Sh + 128 * 64;

    const int tid  = threadIdx.x;
    const int wave = tid >> 6, lane = tid & 63;
    const int m16  = lane & 15, quad = lane >> 4;
    const int wm   = wave >> 1, wn = wave & 1;
    const int n0   = blockIdx.x * 128;
    const int m0   = blockIdx.y * 128;

    f32x4 acc[4][4];   // [nf][mf]
    #pragma unroll
    for (int nf = 0; nf < 4; ++nf)
        #pragma unroll
        for (int mf = 0; mf < 4; ++mf)
            acc[nf][mf] = (f32x4){0.f, 0.f, 0.f, 0.f};

    const int lrow = lane >> 3;          // 0..7
    const int lcol = (lane & 7) << 3;    // 0,8,..,56

    int a_srow[4];
    #pragma unroll
    for (int j = 0; j < 4; ++j) {
        int r = m0 + (wave * 4 + j) * 8 + lrow;
        a_srow[j] = (r < M_) ? r : (M_ - 1);
    }

    for (int kk = 0; kk < E_; kk += 64) {
        __syncthreads();
        #pragma unroll
        for (int j = 0; j < 4; ++j) {
            const int i = wave * 4 + j;
            gld16(xbf + (size_t)a_srow[j] * E_ + kk + lcol, &As[i * 512]);
            gld16(WT + (size_t)(n0 + i * 8 + lrow) * E_ + kk + lcol, &Bs[i * 512]);
        }
        __syncthreads();

        #pragma unroll
        for (int kh = 0; kh < 2; ++kh) {
            const int ko = kh * 32 + quad * 8;
            bf16x8 af[4];
            #pragma unroll
            for (int mf = 0; mf < 4; ++mf)
                af[mf] = *(const bf16x8*)&As[(wm * 64 + mf * 16 + m16) * 64 + ko];
            #pragma unroll
            for (int nf = 0; nf < 4; ++nf) {
                const bf16x8 bfr = *(const bf16x8*)&Bs[(wn * 64 + nf * 16 + m16) * 64 + ko];
                #pragma unroll
                for (int mf = 0; mf < 4; ++mf)
                    acc[nf][mf] = __builtin_amdgcn_mfma_f32_16x16x32_bf16(
                        af[mf], bfr, acc[nf][mf], 0, 0, 0);
            }
        }
    }

    const int z = n0 >> 10;                 // block-uniform
    const int h = ((n0 >> 6) + wn) & 15;    // wave-uniform

    if (z == 2) {
        // v -> transposed [bh][d][S] via LDS-staged coalesced write.
        float biasv[4];
        #pragma unroll
        for (int nf = 0; nf < 4; ++nf)
            biasv[nf] = bv[h * D_ + nf * 16 + m16];

        __syncthreads();   // all waves' final As/Bs reads done before reuse
        #pragma unroll
        for (int mf = 0; mf < 4; ++mf)
            #pragma unroll
            for (int r = 0; r < 4; ++r) {
                const int ml = wm * 64 + mf * 16 + quad * 4 + r;   // 0..127
                #pragma unroll
                for (int nf = 0; nf < 4; ++nf) {
                    const int nl = wn * 64 + nf * 16 + m16;        // 0..127
                    const int idx = (nl * 128 + ml) ^ ((nl & 7) << 3);
                    Sh[idx] = f2bf(acc[nf][mf][r] + biasv[nf]);
                }
            }
        __syncthreads();
        #pragma unroll
        for (int p = 0; p < 8; ++p) {
            const int idxl  = p * 256 + tid;       // 0..2047
            const int row   = idxl >> 4;           // n-local 0..127
            const int chunk = idxl & 15;           // 16B chunk within row
            const int mg    = m0 + chunk * 8;      // global m base (8-aligned)
            if (mg < M_) {                          // batch bdry 1000%8==0: no straddle
                const int bb = mg / S_, ss = mg % S_;
                const int hh = ((n0 >> 6) + (row >> 6)) & 15;
                const int dd = row & 63;
                const int sidx = (row * 128 + chunk * 8) ^ ((row & 7) << 3);
                *(u16x8*)(vt + ((size_t)bb * H_ + hh) * (size_t)(D_ * S_)
                              + (size_t)dd * S_ + ss) = *(const u16x8*)&Sh[sidx];
            }
        }
    } else {
        // q (pre-scaled) or k, layout [b][h][s][d]
        const float qscale = (z == 0)
            ? (0.031622776601683794f * 1.4426950408889634f) : 1.0f;
        unsigned short* const ob = (z == 0) ? qb : kb;
        const float* const bz    = (z == 0) ? bq : bk;

        float biasv[4];
        #pragma unroll
        for (int nf = 0; nf < 4; ++nf)
            biasv[nf] = bz[h * D_ + nf * 16 + m16];

        #pragma unroll
        for (int mf = 0; mf < 4; ++mf)
            #pragma unroll
            for (int r = 0; r < 4; ++r) {
                const int row = m0 + wm * 64 + mf * 16 + quad * 4 + r;
                if (row < M_) {
                    const int b = row / S_, s = row % S_;
                    const size_t obase = (((size_t)b * H_ + h) * S_ + s) * D_ + m16;
                    #pragma unroll
                    for (int nf = 0; nf < 4; ++nf)
                        ob[obase + nf * 16] =
                            f2bf((acc[nf][mf][r] + biasv[nf]) * qscale);
                }
            }
    }
}

// ---------------------------------------------------------------------------
// Flash attention. 8 waves (512 thr), QBLK=128, KVBLK=64.
// R17: K/V DOUBLE-BUFFER, ONE barrier per tile (was 2). Loop = {issue next
// K/V global loads; QK^T from Ks[cur]; softmax->Ps; PV from Vt[cur];
// ds_write next into buf^1; barrier}. This is T14 issue-early/write-late:
// HBM latency hides under the tile's compute; the ds_write drains (lgkm)
// at the barrier, cheap. The GEMM-dbuf failure (R11/R13) was vmcnt(0)
// draining DMA loads at the barrier — reg-staging here doesn't have that.
// LDS 36.9 -> 55.3 KB: 2 blocks/CU (16 waves/CU, was 32) — the risk axis.
// Prologue: Q-frag reads get their own barrier before the loop because the
// first in-loop Ps write (QP union) now has no barrier ahead of it.
// ---------------------------------------------------------------------------
__global__ __launch_bounds__(512) void attn_flash_kernel(
    const unsigned short* __restrict__ q, const unsigned short* __restrict__ k,
    const unsigned short* __restrict__ vt, unsigned short* __restrict__ ybf)
{
    constexpr int P_ = 72;
    __shared__ unsigned short QP[9216];         // Q staging (8192) / Ps[8][16*P_]
    __shared__ unsigned short Ks[2][64 * P_];   // 18.4 KB
    __shared__ unsigned short Vt[2][64 * P_];   // 18.4 KB  [d][t]

    const int tid  = threadIdx.x;
    const int wave = tid >> 6, lane = tid & 63;
    const int m16  = lane & 15, quad = lane >> 4;
    const int jq = (int)gridDim.x - 1 - (int)blockIdx.x;   // long blocks first
    const int h = blockIdx.y, b = blockIdx.z;
    const size_t bh  = ((size_t)b * H_ + h) * S_;
    const size_t vtb = ((size_t)b * H_ + h) * (size_t)D_ * S_;

    const int c8 = (tid & 7) * 8;
    const int r0 = tid >> 3;   // 0..63

    // stage Q (pre-scaled) via DMA: 16 issues x 1024B cover 128 rows
    #pragma unroll
    for (int j = 0; j < 2; ++j) {
        const int i = wave * 2 + j;              // 0..15, wave-uniform
        int srow = jq * 128 + i * 8 + (lane >> 3);
        if (srow >= S_) srow = S_ - 1;           // clamp: valid data, unused rows
        gld16(q + (bh + srow) * D_ + (lane & 7) * 8, &QP[i * 512]);
    }

    // KV tile 0 -> buf 0 (keys 0..63, always valid)
    {
        const u16x8 k0 = *(const u16x8*)(k + (bh + r0) * D_ + c8);
        const u16x8 v0 = *(const u16x8*)(vt + vtb + (size_t)r0 * S_ + c8);
        *(u16x8*)&Ks[0][r0 * P_ + c8] = k0;
        *(u16x8*)&Vt[0][r0 * P_ + c8] = v0;
    }
    __syncthreads();   // Q staged (vmcnt) + KV buf0 written (lgkm)

    const bf16x8 qa0 = *(const bf16x8*)&QP[(wave * 16 + m16) * 64 + quad * 8];
    const bf16x8 qa1 = *(const bf16x8*)&QP[(wave * 16 + m16) * 64 + 32 + quad * 8];
    __syncthreads();   // all waves' Q-frag reads done before first Ps write

    f32x4 O[4] = {{0,0,0,0},{0,0,0,0},{0,0,0,0},{0,0,0,0}};
    float l_i[4] = {0.f, 0.f, 0.f, 0.f};

    const int qrow_base = jq * 128 + wave * 16 + quad * 4;
    const int nt = 2 * jq + 2;   // 64-key tiles for this q-block

    int cur = 0;
    for (int tt = 0; tt < nt; ++tt) {
        const int t0 = tt * 64;

        // issue next-tile loads early; consumed by ds_write at loop bottom
        u16x8 kn = {0,0,0,0,0,0,0,0}, vn = {0,0,0,0,0,0,0,0};
        const bool havenext = (tt + 1 < nt);
        if (havenext) {
            const int nt0 = t0 + 64;
            const int srow = nt0 + r0;
            if (srow < S_) kn = *(const u16x8*)(k + (bh + srow) * D_ + c8);
            if (nt0 + c8 < S_)
                vn = *(const u16x8*)(vt + vtb + (size_t)r0 * S_ + nt0 + c8);
        }

        f32x4 sc[4];
        __builtin_amdgcn_s_setprio(1);
        #pragma unroll
        for (int ts = 0; ts < 4; ++ts) {
            const bf16x8 kb0 = *(const bf16x8*)&Ks[cur][(ts * 16 + m16) * P_ + quad * 8];
            const bf16x8 kb1 = *(const bf16x8*)&Ks[cur][(ts * 16 + m16) * P_ + 32 + quad * 8];
            f32x4 a = {0.f, 0.f, 0.f, 0.f};
            a = __builtin_amdgcn_mfma_f32_16x16x32_bf16(qa0, kb0, a, 0, 0, 0);
            a = __builtin_amdgcn_mfma_f32_16x16x32_bf16(qa1, kb1, a, 0, 0, 0);
            sc[ts] = a;
        }
        __builtin_amdgcn_s_setprio(0);

        unsigned short* const pw = &QP[wave * (16 * P_)];
        if (tt >= nt - 2) {
            #pragma unroll
            for (int ts = 0; ts < 4; ++ts) {
                const int t = t0 + ts * 16 + m16;
                #pragma unroll
                for (int r = 0; r < 4; ++r) {
                    float p = __builtin_amdgcn_exp2f(sc[ts][r]);
                    p = (t <= qrow_base + r) ? p : 0.f;
                    pw[(quad * 4 + r) * P_ + ts * 16 + m16] = f2bf_fast(p);
                    l_i[r] += p;
                }
            }
        } else {
            #pragma unroll
            for (int ts = 0; ts < 4; ++ts)
                #pragma unroll
                for (int r = 0; r < 4; ++r) {
                    const float p = __builtin_amdgcn_exp2f(sc[ts][r]);
                    pw[(quad * 4 + r) * P_ + ts * 16 + m16] = f2bf_fast(p);
                    l_i[r] += p;
                }
        }

        const bf16x8 pa0 = *(const bf16x8*)&pw[m16 * P_ + quad * 8];
        const bf16x8 pa1 = *(const bf16x8*)&pw[m16 * P_ + 32 + quad * 8];
        __builtin_amdgcn_s_setprio(1);
        #pragma unroll
        for (int db = 0; db < 4; ++db) {
            const bf16x8 vb0 = *(const bf16x8*)&Vt[cur][(db * 16 + m16) * P_ + quad * 8];
            const bf16x8 vb1 = *(const bf16x8*)&Vt[cur][(db * 16 + m16) * P_ + 32 + quad * 8];
            O[db] = __builtin_amdgcn_mfma_f32_16x16x32_bf16(pa0, vb0, O[db], 0, 0, 0);
            O[db] = __builtin_amdgcn_mfma_f32_16x16x32_bf16(pa1, vb1, O[db], 0, 0, 0);
        }
        __builtin_amdgcn_s_setprio(0);

        // write next tile into the other buffer; its readers were separated
        // by the barrier at the end of the PREVIOUS iteration.
        if (havenext) {
            *(u16x8*)&Ks[cur ^ 1][r0 * P_ + c8] = kn;
            *(u16x8*)&Vt[cur ^ 1][r0 * P_ + c8] = vn;
        }
        __syncthreads();
        cur ^= 1;
    }

    #pragma unroll
    for (int off = 1; off < 16; off <<= 1)
        #pragma unroll
        for (int r = 0; r < 4; ++r)
            l_i[r] += __shfl_xor(l_i[r], off, 64);

    #pragma unroll
    for (int r = 0; r < 4; ++r) {
        const int qrow = qrow_base + r;
        if (qrow < S_) {
            const float invl = 1.0f / l_i[r];
            #pragma unroll
            for (int db = 0; db < 4; ++db)
                ybf[((size_t)b * S_ + qrow) * E_ + h * D_ + db * 16 + m16] =
                    f2bf(O[db][r] * invl);
        }
    }
}

// ---------------------------------------------------------------------------
// proj + exact GELU. m97 gload_lds 2-barrier single-buffer (R14-proven).
// grid (63 m-fast, 8 n): 63 consecutive blocks share one 256 KB B-panel.
// ---------------------------------------------------------------------------
__global__ __launch_bounds__(256) void proj_mfma_kernel(
    const unsigned short* __restrict__ ybf, const unsigned short* __restrict__ wpT,
    const float* __restrict__ bp, float* __restrict__ out)
{
    __shared__ unsigned short As[128 * 64];   // 16 KB, linear
    __shared__ unsigned short Bs[128 * 64];   // 16 KB, linear

    const int tid = threadIdx.x;
    const int wave = tid >> 6, lane = tid & 63;
    const int m16 = lane & 15, quad = lane >> 4;
    const int wm = wave >> 1, wn = wave & 1;
    const int m0 = blockIdx.x * 128;
    const int n0 = blockIdx.y * 128;

    f32x4 acc[4][4];
    #pragma unroll
    for (int nf = 0; nf < 4; ++nf)
        #pragma unroll
        for (int mf = 0; mf < 4; ++mf)
            acc[nf][mf] = (f32x4){0.f, 0.f, 0.f, 0.f};

    const int lrow = lane >> 3;          // 0..7
    const int lcol = (lane & 7) << 3;    // 0,8,..,56

    int a_srow[4];
    #pragma unroll
    for (int j = 0; j < 4; ++j) {
        int r = m0 + (wave * 4 + j) * 8 + lrow;
        a_srow[j] = (r < M_) ? r : (M_ - 1);
    }

    for (int kk = 0; kk < E_; kk += 64) {
        __syncthreads();
        #pragma unroll
        for (int j = 0; j < 4; ++j) {
            const int i = wave * 4 + j;
            gld16(ybf + (size_t)a_srow[j] * E_ + kk + lcol, &As[i * 512]);
            gld16(wpT + (size_t)(n0 + i * 8 + lrow) * E_ + kk + lcol, &Bs[i * 512]);
        }
        __syncthreads();

        #pragma unroll
        for (int kh = 0; kh < 2; ++kh) {
            const int ko = kh * 32 + quad * 8;
            bf16x8 af[4];
            #pragma unroll
            for (int mf = 0; mf < 4; ++mf)
                af[mf] = *(const bf16x8*)&As[(wm * 64 + mf * 16 + m16) * 64 + ko];
            #pragma unroll
            for (int nf = 0; nf < 4; ++nf) {
                const bf16x8 bfr = *(const bf16x8*)&Bs[(wn * 64 + nf * 16 + m16) * 64 + ko];
                #pragma unroll
                for (int mf = 0; mf < 4; ++mf)
                    acc[nf][mf] = __builtin_amdgcn_mfma_f32_16x16x32_bf16(
                        af[mf], bfr, acc[nf][mf], 0, 0, 0);
            }
        }
    }

    float biasv[4];
    #pragma unroll
    for (int nf = 0; nf < 4; ++nf)
        biasv[nf] = bp[n0 + wn * 64 + nf * 16 + m16];

    #pragma unroll
    for (int mf = 0; mf < 4; ++mf)
        #pragma unroll
        for (int r = 0; r < 4; ++r) {
            const int row = m0 + wm * 64 + mf * 16 + quad * 4 + r;
            if (row < M_) {
                #pragma unroll
                for (int nf = 0; nf < 4; ++nf) {
                    const int col = n0 + wn * 64 + nf * 16 + m16;
                    const float t = acc[nf][mf][r] + biasv[nf];
                    const float g = 0.5f * t * (1.0f + erff(t * 0.70710678118654752f));
                    out[(size_t)row * E_ + col] = g;
                }
            }
        }
}

// ---------------------------------------------------------------------------
extern "C" void kernel_launch(void* const* d_in, const int* in_sizes, int n_in,
                              void* d_out, int out_size, void* d_ws, size_t ws_size,
                              hipStream_t stream)
{
    const float* x  = (const float*)d_in[0];
    const float* wq = (const float*)d_in[1];
    const float* bq = (const float*)d_in[2];
    const float* wk = (const float*)d_in[3];
    const float* bk = (const float*)d_in[4];
    const float* wv = (const float*)d_in[5];
    const float* bv = (const float*)d_in[6];
    const float* wp = (const float*)d_in[7];
    const float* bp = (const float*)d_in[8];
    float* out = (float*)d_out;

    const size_t nME = (size_t)M_ * E_;          // 8,192,000
    unsigned short* xbf = (unsigned short*)d_ws;
    unsigned short* WT  = xbf + nME;             // 3,145,728
    unsigned short* wpT = WT + 3145728;          // 1,048,576
    unsigned short* qb  = wpT + 1048576;
    unsigned short* kb  = qb + nME;
    unsigned short* vtr = kb + nME;              // v transposed [bh][d][S] (direct from qkv)
    unsigned short* ybf = vtr + nME;

    cast_x_kernel<<<dim3((unsigned)(nME / 1024)), 256, 0, stream>>>(x, xbf);
    transpose_w_kernel<<<dim3(16, 64), 256, 0, stream>>>(wq, wk, wv, wp, WT, wpT);

    // Single-GEMM qkv: grid (N-tiles=24 fastest, M-tiles=63).
    // Writes q pre-scaled, k, and v directly transposed.
    qkv_mfma_kernel<<<dim3(3072 / 128, (M_ + 127) / 128), 256, 0, stream>>>(
        xbf, WT, bq, bk, bv, qb, kb, vtr);
    attn_flash_kernel<<<dim3((S_ + 127) / 128, H_, B_), 512, 0, stream>>>(
        qb, kb, vtr, ybf);
    proj_mfma_kernel<<<dim3((M_ + 127) / 128, E_ / 128), 256, 0, stream>>>(
        ybf, wpT, bp, out);
}

// Round 10
// 273.307 us; speedup vs baseline: 1.0669x; 1.0096x over previous
//
#include <hip/hip_runtime.h>
#include <hip/hip_bf16.h>
#include <math.h>

// Problem constants: B=8, S=1000, E=1024, H=16, D=64
constexpr int B_ = 8, S_ = 1000, E_ = 1024, H_ = 16, D_ = 64;
constexpr int M_ = B_ * S_;   // 8000 rows

using bf16x8 = __attribute__((ext_vector_type(8))) __bf16;
using u16x8  = __attribute__((ext_vector_type(8))) unsigned short;
using f32x4  = __attribute__((ext_vector_type(4))) float;

static __device__ __forceinline__ unsigned short f2bf(float f) {
    union { float f; unsigned u; } c; c.f = f;
    return (unsigned short)((c.u + 0x7FFF + ((c.u >> 16) & 1)) >> 16);
}
static __device__ __forceinline__ unsigned short f2bf_fast(float f) {
    union { float f; unsigned u; } c; c.f = f;
    return (unsigned short)((c.u + 0x8000) >> 16);   // round-half-up
}
static __device__ __forceinline__ float bfr2f(unsigned short s) {
    union { unsigned u; float f; } c; c.u = ((unsigned)s) << 16;
    return c.f;
}

// Async global->LDS DMA, 16B per lane. LDS dest is wave-uniform base;
// HW writes base + lane*16 (linear). Global source is per-lane.
static __device__ __forceinline__ void gld16(const unsigned short* g, unsigned short* lds) {
    __builtin_amdgcn_global_load_lds(
        (__attribute__((address_space(1))) void*)(g),
        (__attribute__((address_space(3))) void*)(lds), 16, 0, 0);
}

// ---------------------------------------------------------------------------
// R18 prep kernel: cast_x + all weight transposes in ONE launch.
//   bid <  8000:        x fp32 [M,E] -> xbf bf16 (1024 els/block)
//   bid >= 8000, t=bid-8000: et=t&15, y=t>>4:
//     y in [0,48):  w{q,k,v}[h][e][d] -> WT[(z*16+h)*64+d][e]
//     y in [48,64): wp[e][f] -> wpT[f][e], ft=y-48
// Independent work; merging removes a launch gap and overlaps the
// LDS-transpose blocks with the memory-bound cast blocks.
// ---------------------------------------------------------------------------
__global__ __launch_bounds__(256) void prep_kernel(
    const float* __restrict__ x,
    const float* __restrict__ wq, const float* __restrict__ wk,
    const float* __restrict__ wv, const float* __restrict__ wp,
    unsigned short* __restrict__ xbf,
    unsigned short* __restrict__ WT, unsigned short* __restrict__ wpT)
{
    __shared__ unsigned short Ts[64 * 65];
    const int bid = blockIdx.x;

    if (bid < 8000) {
        const size_t i = ((size_t)bid * 256 + threadIdx.x) * 4;
        float4 v = *(const float4*)(x + i);
        ushort4 o;
        o.x = f2bf(v.x); o.y = f2bf(v.y); o.z = f2bf(v.z); o.w = f2bf(v.w);
        *(ushort4*)(xbf + i) = o;
        return;
    }

    const int t  = bid - 8000;
    const int et = t & 15, y = t >> 4;

    if (y < 48) {
        const int z = y >> 4, h = y & 15;
        const float* src = (z == 0 ? wq : z == 1 ? wk : wv) + (size_t)h * E_ * D_;
        const int d = threadIdx.x & 63;
        const int e0 = threadIdx.x >> 6;   // 0..3
        #pragma unroll
        for (int p = 0; p < 16; ++p) {
            const int e = e0 + p * 4;
            Ts[d * 65 + e] = f2bf(src[(size_t)(et * 64 + e) * D_ + d]);
        }
        __syncthreads();
        const int e = threadIdx.x & 63;
        const int d0 = threadIdx.x >> 6;
        #pragma unroll
        for (int p = 0; p < 16; ++p) {
            const int dd = d0 + p * 4;
            WT[((size_t)y * 64 + dd) * E_ + et * 64 + e] = Ts[dd * 65 + e];
        }
    } else {
        const int ft = y - 48;
        const int f = threadIdx.x & 63;
        const int e0 = threadIdx.x >> 6;
        #pragma unroll
        for (int p = 0; p < 16; ++p) {
            const int e = e0 + p * 4;
            Ts[f * 65 + e] = f2bf(wp[(size_t)(et * 64 + e) * E_ + ft * 64 + f]);
        }
        __syncthreads();
        const int e = threadIdx.x & 63;
        const int f0 = threadIdx.x >> 6;
        #pragma unroll
        for (int p = 0; p < 16; ++p) {
            const int ff = f0 + p * 4;
            wpT[((size_t)(ft * 64 + ff)) * E_ + et * 64 + e] = Ts[ff * 65 + e];
        }
    }
}

// ---------------------------------------------------------------------------
// qkv projection: ONE dense GEMM [M=8000,K=1024] x [K,N=3072].
// 2-barrier single-buffer m97 form (measured best; dbuf/XCD-swizzle regress,
// see R11-R14). Epilogue fusions (R16/R17-proven, qkv at 90.2-90.7us):
//   - z==0 (q): pre-scaled by 1/sqrt(S)*log2e.
//   - z==2 (v): TRANSPOSED [bh][d][S] via LDS-staged coalesce (direct
//     scatter was issue-bound: 64 lines/wave-store, +16us — R16 lesson).
// ---------------------------------------------------------------------------
__global__ __launch_bounds__(256) void qkv_mfma_kernel(
    const unsigned short* __restrict__ xbf, const unsigned short* __restrict__ WT,
    const float* __restrict__ bq, const float* __restrict__ bk,
    const float* __restrict__ bv,
    unsigned short* __restrict__ qb, unsigned short* __restrict__ kb,
    unsigned short* __restrict__ vt)
{
    __shared__ unsigned short Sh[2 * 128 * 64];   // 32 KB: As | Bs, reused as Ts
    unsigned short* const As = Sh;
    unsigned short* const Bs = Sh + 128 * 64;

    const int tid  = threadIdx.x;
    const int wave = tid >> 6, lane = tid & 63;
    const int m16  = lane & 15, quad = lane >> 4;
    const int wm   = wave >> 1, wn = wave & 1;
    const int n0   = blockIdx.x * 128;
    const int m0   = blockIdx.y * 128;

    f32x4 acc[4][4];   // [nf][mf]
    #pragma unroll
    for (int nf = 0; nf < 4; ++nf)
        #pragma unroll
        for (int mf = 0; mf < 4; ++mf)
            acc[nf][mf] = (f32x4){0.f, 0.f, 0.f, 0.f};

    const int lrow = lane >> 3;          // 0..7
    const int lcol = (lane & 7) << 3;    // 0,8,..,56

    int a_srow[4];
    #pragma unroll
    for (int j = 0; j < 4; ++j) {
        int r = m0 + (wave * 4 + j) * 8 + lrow;
        a_srow[j] = (r < M_) ? r : (M_ - 1);
    }

    for (int kk = 0; kk < E_; kk += 64) {
        __syncthreads();
        #pragma unroll
        for (int j = 0; j < 4; ++j) {
            const int i = wave * 4 + j;
            gld16(xbf + (size_t)a_srow[j] * E_ + kk + lcol, &As[i * 512]);
            gld16(WT + (size_t)(n0 + i * 8 + lrow) * E_ + kk + lcol, &Bs[i * 512]);
        }
        __syncthreads();

        #pragma unroll
        for (int kh = 0; kh < 2; ++kh) {
            const int ko = kh * 32 + quad * 8;
            bf16x8 af[4];
            #pragma unroll
            for (int mf = 0; mf < 4; ++mf)
                af[mf] = *(const bf16x8*)&As[(wm * 64 + mf * 16 + m16) * 64 + ko];
            #pragma unroll
            for (int nf = 0; nf < 4; ++nf) {
                const bf16x8 bfr = *(const bf16x8*)&Bs[(wn * 64 + nf * 16 + m16) * 64 + ko];
                #pragma unroll
                for (int mf = 0; mf < 4; ++mf)
                    acc[nf][mf] = __builtin_amdgcn_mfma_f32_16x16x32_bf16(
                        af[mf], bfr, acc[nf][mf], 0, 0, 0);
            }
        }
    }

    const int z = n0 >> 10;                 // block-uniform
    const int h = ((n0 >> 6) + wn) & 15;    // wave-uniform

    if (z == 2) {
        // v -> transposed [bh][d][S] via LDS-staged coalesced write.
        float biasv[4];
        #pragma unroll
        for (int nf = 0; nf < 4; ++nf)
            biasv[nf] = bv[h * D_ + nf * 16 + m16];

        __syncthreads();   // all waves' final As/Bs reads done before reuse
        #pragma unroll
        for (int mf = 0; mf < 4; ++mf)
            #pragma unroll
            for (int r = 0; r < 4; ++r) {
                const int ml = wm * 64 + mf * 16 + quad * 4 + r;   // 0..127
                #pragma unroll
                for (int nf = 0; nf < 4; ++nf) {
                    const int nl = wn * 64 + nf * 16 + m16;        // 0..127
                    const int idx = (nl * 128 + ml) ^ ((nl & 7) << 3);
                    Sh[idx] = f2bf(acc[nf][mf][r] + biasv[nf]);
                }
            }
        __syncthreads();
        #pragma unroll
        for (int p = 0; p < 8; ++p) {
            const int idxl  = p * 256 + tid;       // 0..2047
            const int row   = idxl >> 4;           // n-local 0..127
            const int chunk = idxl & 15;           // 16B chunk within row
            const int mg    = m0 + chunk * 8;      // global m base (8-aligned)
            if (mg < M_) {                          // batch bdry 1000%8==0: no straddle
                const int bb = mg / S_, ss = mg % S_;
                const int hh = ((n0 >> 6) + (row >> 6)) & 15;
                const int dd = row & 63;
                const int sidx = (row * 128 + chunk * 8) ^ ((row & 7) << 3);
                *(u16x8*)(vt + ((size_t)bb * H_ + hh) * (size_t)(D_ * S_)
                              + (size_t)dd * S_ + ss) = *(const u16x8*)&Sh[sidx];
            }
        }
    } else {
        // q (pre-scaled) or k, layout [b][h][s][d]
        const float qscale = (z == 0)
            ? (0.031622776601683794f * 1.4426950408889634f) : 1.0f;
        unsigned short* const ob = (z == 0) ? qb : kb;
        const float* const bz    = (z == 0) ? bq : bk;

        float biasv[4];
        #pragma unroll
        for (int nf = 0; nf < 4; ++nf)
            biasv[nf] = bz[h * D_ + nf * 16 + m16];

        #pragma unroll
        for (int mf = 0; mf < 4; ++mf)
            #pragma unroll
            for (int r = 0; r < 4; ++r) {
                const int row = m0 + wm * 64 + mf * 16 + quad * 4 + r;
                if (row < M_) {
                    const int b = row / S_, s = row % S_;
                    const size_t obase = (((size_t)b * H_ + h) * S_ + s) * D_ + m16;
                    #pragma unroll
                    for (int nf = 0; nf < 4; ++nf)
                        ob[obase + nf * 16] =
                            f2bf((acc[nf][mf][r] + biasv[nf]) * qscale);
                }
            }
    }
}

// ---------------------------------------------------------------------------
// Flash attention. 8 waves (512 thr), QBLK=128, KVBLK=64, K/V dbuf with one
// barrier per tile (R17-proven). R18 additions (both wave-uniform branches):
//   - FULL SKIP of a tile's compute when it is entirely causal-masked for
//     this wave (t0 > wave_qmin+15): waves 0-3 skip the last diagonal tile
//     (8 MFMA + 32 exp2 + Ps traffic of pure zeros). Barriers + staging
//     still execute on all waves.
//   - Exact mask predicate (t0+63 > wave_qmin) instead of tile-index
//     (tt>=nt-2): waves 4-7 use the maskless path on tile 2jq.
// Key tail: keys 1000..1023 only reach waves where the mask predicate is
// true (t0+63=1023 > wave_qmin<=1008), handled by p=0 as before.
// ---------------------------------------------------------------------------
__global__ __launch_bounds__(512) void attn_flash_kernel(
    const unsigned short* __restrict__ q, const unsigned short* __restrict__ k,
    const unsigned short* __restrict__ vt, unsigned short* __restrict__ ybf)
{
    constexpr int P_ = 72;
    __shared__ unsigned short QP[9216];         // Q staging (8192) / Ps[8][16*P_]
    __shared__ unsigned short Ks[2][64 * P_];   // 18.4 KB
    __shared__ unsigned short Vt[2][64 * P_];   // 18.4 KB  [d][t]

    const int tid  = threadIdx.x;
    const int wave = tid >> 6, lane = tid & 63;
    const int m16  = lane & 15, quad = lane >> 4;
    const int jq = (int)gridDim.x - 1 - (int)blockIdx.x;   // long blocks first
    const int h = blockIdx.y, b = blockIdx.z;
    const size_t bh  = ((size_t)b * H_ + h) * S_;
    const size_t vtb = ((size_t)b * H_ + h) * (size_t)D_ * S_;

    const int c8 = (tid & 7) * 8;
    const int r0 = tid >> 3;   // 0..63

    // stage Q (pre-scaled) via DMA: 16 issues x 1024B cover 128 rows
    #pragma unroll
    for (int j = 0; j < 2; ++j) {
        const int i = wave * 2 + j;              // 0..15, wave-uniform
        int srow = jq * 128 + i * 8 + (lane >> 3);
        if (srow >= S_) srow = S_ - 1;           // clamp: valid data, unused rows
        gld16(q + (bh + srow) * D_ + (lane & 7) * 8, &QP[i * 512]);
    }

    // KV tile 0 -> buf 0 (keys 0..63, always valid)
    {
        const u16x8 k0 = *(const u16x8*)(k + (bh + r0) * D_ + c8);
        const u16x8 v0 = *(const u16x8*)(vt + vtb + (size_t)r0 * S_ + c8);
        *(u16x8*)&Ks[0][r0 * P_ + c8] = k0;
        *(u16x8*)&Vt[0][r0 * P_ + c8] = v0;
    }
    __syncthreads();   // Q staged (vmcnt) + KV buf0 written (lgkm)

    const bf16x8 qa0 = *(const bf16x8*)&QP[(wave * 16 + m16) * 64 + quad * 8];
    const bf16x8 qa1 = *(const bf16x8*)&QP[(wave * 16 + m16) * 64 + 32 + quad * 8];
    __syncthreads();   // all waves' Q-frag reads done before first Ps write

    f32x4 O[4] = {{0,0,0,0},{0,0,0,0},{0,0,0,0},{0,0,0,0}};
    float l_i[4] = {0.f, 0.f, 0.f, 0.f};

    const int wave_qmin = jq * 128 + wave * 16;        // wave-uniform
    const int qrow_base = wave_qmin + quad * 4;
    const int nt = 2 * jq + 2;   // 64-key tiles for this q-block

    int cur = 0;
    for (int tt = 0; tt < nt; ++tt) {
        const int t0 = tt * 64;

        // issue next-tile loads early; consumed by ds_write at loop bottom
        u16x8 kn = {0,0,0,0,0,0,0,0}, vn = {0,0,0,0,0,0,0,0};
        const bool havenext = (tt + 1 < nt);
        if (havenext) {
            const int nt0 = t0 + 64;
            const int srow = nt0 + r0;
            if (srow < S_) kn = *(const u16x8*)(k + (bh + srow) * D_ + c8);
            if (nt0 + c8 < S_)
                vn = *(const u16x8*)(vt + vtb + (size_t)r0 * S_ + nt0 + c8);
        }

        // wave-uniform: skip compute if every key in this tile exceeds every
        // q-row this wave owns (fully masked). Barrier/staging still run.
        if (t0 <= wave_qmin + 15) {
            f32x4 sc[4];
            __builtin_amdgcn_s_setprio(1);
            #pragma unroll
            for (int ts = 0; ts < 4; ++ts) {
                const bf16x8 kb0 = *(const bf16x8*)&Ks[cur][(ts * 16 + m16) * P_ + quad * 8];
                const bf16x8 kb1 = *(const bf16x8*)&Ks[cur][(ts * 16 + m16) * P_ + 32 + quad * 8];
                f32x4 a = {0.f, 0.f, 0.f, 0.f};
                a = __builtin_amdgcn_mfma_f32_16x16x32_bf16(qa0, kb0, a, 0, 0, 0);
                a = __builtin_amdgcn_mfma_f32_16x16x32_bf16(qa1, kb1, a, 0, 0, 0);
                sc[ts] = a;
            }
            __builtin_amdgcn_s_setprio(0);

            unsigned short* const pw = &QP[wave * (16 * P_)];
            if (t0 + 63 > wave_qmin) {   // diagonal for this wave: apply mask
                #pragma unroll
                for (int ts = 0; ts < 4; ++ts) {
                    const int t = t0 + ts * 16 + m16;
                    #pragma unroll
                    for (int r = 0; r < 4; ++r) {
                        float p = __builtin_amdgcn_exp2f(sc[ts][r]);
                        p = (t <= qrow_base + r) ? p : 0.f;
                        pw[(quad * 4 + r) * P_ + ts * 16 + m16] = f2bf_fast(p);
                        l_i[r] += p;
                    }
                }
            } else {
                #pragma unroll
                for (int ts = 0; ts < 4; ++ts)
                    #pragma unroll
                    for (int r = 0; r < 4; ++r) {
                        const float p = __builtin_amdgcn_exp2f(sc[ts][r]);
                        pw[(quad * 4 + r) * P_ + ts * 16 + m16] = f2bf_fast(p);
                        l_i[r] += p;
                    }
            }

            const bf16x8 pa0 = *(const bf16x8*)&pw[m16 * P_ + quad * 8];
            const bf16x8 pa1 = *(const bf16x8*)&pw[m16 * P_ + 32 + quad * 8];
            __builtin_amdgcn_s_setprio(1);
            #pragma unroll
            for (int db = 0; db < 4; ++db) {
                const bf16x8 vb0 = *(const bf16x8*)&Vt[cur][(db * 16 + m16) * P_ + quad * 8];
                const bf16x8 vb1 = *(const bf16x8*)&Vt[cur][(db * 16 + m16) * P_ + 32 + quad * 8];
                O[db] = __builtin_amdgcn_mfma_f32_16x16x32_bf16(pa0, vb0, O[db], 0, 0, 0);
                O[db] = __builtin_amdgcn_mfma_f32_16x16x32_bf16(pa1, vb1, O[db], 0, 0, 0);
            }
            __builtin_amdgcn_s_setprio(0);
        }

        // write next tile into the other buffer; its readers were separated
        // by the barrier at the end of the PREVIOUS iteration.
        if (havenext) {
            *(u16x8*)&Ks[cur ^ 1][r0 * P_ + c8] = kn;
            *(u16x8*)&Vt[cur ^ 1][r0 * P_ + c8] = vn;
        }
        __syncthreads();
        cur ^= 1;
    }

    #pragma unroll
    for (int off = 1; off < 16; off <<= 1)
        #pragma unroll
        for (int r = 0; r < 4; ++r)
            l_i[r] += __shfl_xor(l_i[r], off, 64);

    #pragma unroll
    for (int r = 0; r < 4; ++r) {
        const int qrow = qrow_base + r;
        if (qrow < S_) {
            const float invl = 1.0f / l_i[r];
            #pragma unroll
            for (int db = 0; db < 4; ++db)
                ybf[((size_t)b * S_ + qrow) * E_ + h * D_ + db * 16 + m16] =
                    f2bf(O[db][r] * invl);
        }
    }
}

// ---------------------------------------------------------------------------
// proj + exact GELU. m97 gload_lds 2-barrier single-buffer (R14-proven).
// grid (63 m-fast, 8 n): 63 consecutive blocks share one 256 KB B-panel.
// ---------------------------------------------------------------------------
__global__ __launch_bounds__(256) void proj_mfma_kernel(
    const unsigned short* __restrict__ ybf, const unsigned short* __restrict__ wpT,
    const float* __restrict__ bp, float* __restrict__ out)
{
    __shared__ unsigned short As[128 * 64];   // 16 KB, linear
    __shared__ unsigned short Bs[128 * 64];   // 16 KB, linear

    const int tid = threadIdx.x;
    const int wave = tid >> 6, lane = tid & 63;
    const int m16 = lane & 15, quad = lane >> 4;
    const int wm = wave >> 1, wn = wave & 1;
    const int m0 = blockIdx.x * 128;
    const int n0 = blockIdx.y * 128;

    f32x4 acc[4][4];
    #pragma unroll
    for (int nf = 0; nf < 4; ++nf)
        #pragma unroll
        for (int mf = 0; mf < 4; ++mf)
            acc[nf][mf] = (f32x4){0.f, 0.f, 0.f, 0.f};

    const int lrow = lane >> 3;          // 0..7
    const int lcol = (lane & 7) << 3;    // 0,8,..,56

    int a_srow[4];
    #pragma unroll
    for (int j = 0; j < 4; ++j) {
        int r = m0 + (wave * 4 + j) * 8 + lrow;
        a_srow[j] = (r < M_) ? r : (M_ - 1);
    }

    for (int kk = 0; kk < E_; kk += 64) {
        __syncthreads();
        #pragma unroll
        for (int j = 0; j < 4; ++j) {
            const int i = wave * 4 + j;
            gld16(ybf + (size_t)a_srow[j] * E_ + kk + lcol, &As[i * 512]);
            gld16(wpT + (size_t)(n0 + i * 8 + lrow) * E_ + kk + lcol, &Bs[i * 512]);
        }
        __syncthreads();

        #pragma unroll
        for (int kh = 0; kh < 2; ++kh) {
            const int ko = kh * 32 + quad * 8;
            bf16x8 af[4];
            #pragma unroll
            for (int mf = 0; mf < 4; ++mf)
                af[mf] = *(const bf16x8*)&As[(wm * 64 + mf * 16 + m16) * 64 + ko];
            #pragma unroll
            for (int nf = 0; nf < 4; ++nf) {
                const bf16x8 bfr = *(const bf16x8*)&Bs[(wn * 64 + nf * 16 + m16) * 64 + ko];
                #pragma unroll
                for (int mf = 0; mf < 4; ++mf)
                    acc[nf][mf] = __builtin_amdgcn_mfma_f32_16x16x32_bf16(
                        af[mf], bfr, acc[nf][mf], 0, 0, 0);
            }
        }
    }

    float biasv[4];
    #pragma unroll
    for (int nf = 0; nf < 4; ++nf)
        biasv[nf] = bp[n0 + wn * 64 + nf * 16 + m16];

    #pragma unroll
    for (int mf = 0; mf < 4; ++mf)
        #pragma unroll
        for (int r = 0; r < 4; ++r) {
            const int row = m0 + wm * 64 + mf * 16 + quad * 4 + r;
            if (row < M_) {
                #pragma unroll
                for (int nf = 0; nf < 4; ++nf) {
                    const int col = n0 + wn * 64 + nf * 16 + m16;
                    const float t = acc[nf][mf][r] + biasv[nf];
                    const float g = 0.5f * t * (1.0f + erff(t * 0.70710678118654752f));
                    out[(size_t)row * E_ + col] = g;
                }
            }
        }
}

// ---------------------------------------------------------------------------
extern "C" void kernel_launch(void* const* d_in, const int* in_sizes, int n_in,
                              void* d_out, int out_size, void* d_ws, size_t ws_size,
                              hipStream_t stream)
{
    const float* x  = (const float*)d_in[0];
    const float* wq = (const float*)d_in[1];
    const float* bq = (const float*)d_in[2];
    const float* wk = (const float*)d_in[3];
    const float* bk = (const float*)d_in[4];
    const float* wv = (const float*)d_in[5];
    const float* bv = (const float*)d_in[6];
    const float* wp = (const float*)d_in[7];
    const float* bp = (const float*)d_in[8];
    float* out = (float*)d_out;

    const size_t nME = (size_t)M_ * E_;          // 8,192,000
    unsigned short* xbf = (unsigned short*)d_ws;
    unsigned short* WT  = xbf + nME;             // 3,145,728
    unsigned short* wpT = WT + 3145728;          // 1,048,576
    unsigned short* qb  = wpT + 1048576;
    unsigned short* kb  = qb + nME;
    unsigned short* vtr = kb + nME;              // v transposed [bh][d][S] (direct from qkv)
    unsigned short* ybf = vtr + nME;

    prep_kernel<<<dim3(8000 + 1024), 256, 0, stream>>>(
        x, wq, wk, wv, wp, xbf, WT, wpT);

    // Single-GEMM qkv: grid (N-tiles=24 fastest, M-tiles=63).
    // Writes q pre-scaled, k, and v directly transposed.
    qkv_mfma_kernel<<<dim3(3072 / 128, (M_ + 127) / 128), 256, 0, stream>>>(
        xbf, WT, bq, bk, bv, qb, kb, vtr);
    attn_flash_kernel<<<dim3((S_ + 127) / 128, H_, B_), 512, 0, stream>>>(
        qb, kb, vtr, ybf);
    proj_mfma_kernel<<<dim3((M_ + 127) / 128, E_ / 128), 256, 0, stream>>>(
        ybf, wpT, bp, out);
}